// Round 1
// baseline (304.432 us; speedup 1.0000x reference)
//
#include <hip/hip_runtime.h>
#include <math.h>

// GAU attention: LN -> silu(x@W^T+b) x4 -> P=relu^2(QK^T/sqrt(T)) -> AV=P@V -> (U*AV)@Wo^T+bo
// All GEMMs use the B^T pattern (both operands row-major, contiguous K) with
// 16x16x32 bf16 MFMA, 128x128 tiles, global_load_lds width-16 staging (m97 structure).

typedef __attribute__((ext_vector_type(8))) short short8;
typedef __attribute__((ext_vector_type(4))) float floatx4;

constexpr int HD = 768;
constexpr int TT = 2048;
constexpr long WElem = 589824;   // 768*768

__device__ __forceinline__ short f2bf(float x) {
  unsigned u = __builtin_bit_cast(unsigned, x);
  u = u + 0x7fffu + ((u >> 16) & 1u);   // RNE
  return (short)(u >> 16);
}
__device__ __forceinline__ float bf2f(short s) {
  unsigned u = ((unsigned)(unsigned short)s) << 16;
  return __builtin_bit_cast(float, u);
}

__device__ __forceinline__ void async_ld16(const short* g, void* l) {
  __builtin_amdgcn_global_load_lds(
      (const __attribute__((address_space(1))) unsigned int*)g,
      (__attribute__((address_space(3))) unsigned int*)l, 16, 0, 0);
}

// ---------------- LayerNorm + bf16 cast: one block per row (768 elems) -------------
__global__ __launch_bounds__(256) void ln_kernel(
    const float* __restrict__ x, const float* __restrict__ g,
    const float* __restrict__ b, short* __restrict__ out) {
  int row = blockIdx.x;
  const float* xr = x + (long)row * HD;
  int t = threadIdx.x;
  float v0 = xr[t], v1 = xr[t + 256], v2 = xr[t + 512];
  float s = v0 + v1 + v2;
  float ss = v0 * v0 + v1 * v1 + v2 * v2;
#pragma unroll
  for (int o = 32; o > 0; o >>= 1) {
    s += __shfl_down(s, o);
    ss += __shfl_down(ss, o);
  }
  __shared__ float red[8];
  int wid = t >> 6;
  if ((t & 63) == 0) { red[wid] = s; red[4 + wid] = ss; }
  __syncthreads();
  float S = red[0] + red[1] + red[2] + red[3];
  float SS = red[4] + red[5] + red[6] + red[7];
  float mean = S * (1.0f / HD);
  float var = SS * (1.0f / HD) - mean * mean;
  float rstd = rsqrtf(var + 1e-5f);
  short* orow = out + (long)row * HD;
  orow[t]       = f2bf((v0 - mean) * rstd * g[t]       + b[t]);
  orow[t + 256] = f2bf((v1 - mean) * rstd * g[t + 256] + b[t + 256]);
  orow[t + 512] = f2bf((v2 - mean) * rstd * g[t + 512] + b[t + 512]);
}

// ---------------- fp32 -> bf16 weight conversion + bias concat ---------------------
__global__ __launch_bounds__(256) void convert_kernel(
    const float* __restrict__ wu, const float* __restrict__ wq,
    const float* __restrict__ wk, const float* __restrict__ wv,
    const float* __restrict__ wo,
    const float* __restrict__ bu, const float* __restrict__ bq,
    const float* __restrict__ bk, const float* __restrict__ bv,
    short* __restrict__ Wb, float* __restrict__ bcat) {
  long i = (long)blockIdx.x * 256 + threadIdx.x;
  if (i < 5 * WElem) {
    int which = (int)(i / WElem);
    long off = i - (long)which * WElem;
    const float* src = which == 0 ? wu : which == 1 ? wq : which == 2 ? wk
                     : which == 3 ? wv : wo;
    Wb[i] = f2bf(src[off]);
  }
  if (i < 4 * HD) {
    int which = (int)(i / HD);
    int off = (int)(i - which * HD);
    const float* src = which == 0 ? bu : which == 1 ? bq : which == 2 ? bk : bv;
    bcat[i] = src[off];
  }
}

// ---------------- B^T GEMM, 128x128 tile, BK=32, 4 waves (2x2), 4x4 MFMA/wave ------
// EPI 0: silu(acc+bias) -> U/Q/K bf16 row-major, V transposed (Vt[d][t])
// EPI 1: relu(acc*rs)^2 -> P bf16
// EPI 2: acc * U       -> G bf16
// EPI 3: acc + bias    -> fp32 d_out
template <int EPI>
__global__ __launch_bounds__(256, 2) void gemm_bt(
    const short* __restrict__ Ag, const short* __restrict__ Bg,
    int K, int lda, int ldb, long sAz, long sBz,
    short* __restrict__ o0, short* __restrict__ o1,
    short* __restrict__ o2, short* __restrict__ o3,
    float* __restrict__ outf, const float* __restrict__ bias,
    const short* __restrict__ umul) {
  __shared__ short As[128 * 32];
  __shared__ short Bs[128 * 32];
  int z = blockIdx.z;
  const short* Ab = Ag + (long)z * sAz;
  const short* Bb = Bg + (long)z * sBz;
  int m0 = blockIdx.y * 128, n0 = blockIdx.x * 128;
  int t = threadIdx.x;
  int w = t >> 6, lane = t & 63;
  int wm = (w >> 1) * 64, wn = (w & 1) * 64;
  int qd = lane >> 4, l15 = lane & 15;

  floatx4 acc[4][4] = {};

  // staging: thread t loads 16B for rows t>>2 and 64+(t>>2)
  int r0 = t >> 2;
  int c0 = (t & 3) * 8;
  const short* aSrc0 = Ab + (long)(m0 + r0) * lda + c0;
  const short* aSrc1 = Ab + (long)(m0 + 64 + r0) * lda + c0;
  const short* bSrc0 = Bb + (long)(n0 + r0) * ldb + c0;
  const short* bSrc1 = Bb + (long)(n0 + 64 + r0) * ldb + c0;
  // wave-uniform LDS bases (bytes): lane l lands at base + l*16
  char* aL0 = (char*)As + w * 1024;
  char* aL1 = (char*)As + 4096 + w * 1024;
  char* bL0 = (char*)Bs + w * 1024;
  char* bL1 = (char*)Bs + 4096 + w * 1024;

  for (int k0 = 0; k0 < K; k0 += 32) {
    __syncthreads();
    async_ld16(aSrc0, aL0);
    async_ld16(aSrc1, aL1);
    async_ld16(bSrc0, bL0);
    async_ld16(bSrc1, bL1);
    aSrc0 += 32; aSrc1 += 32; bSrc0 += 32; bSrc1 += 32;
    __syncthreads();

    short8 af[4], bf[4];
#pragma unroll
    for (int mi = 0; mi < 4; mi++)
      af[mi] = *(const short8*)&As[(wm + mi * 16 + l15) * 32 + qd * 8];
#pragma unroll
    for (int ni = 0; ni < 4; ni++)
      bf[ni] = *(const short8*)&Bs[(wn + ni * 16 + l15) * 32 + qd * 8];
#pragma unroll
    for (int mi = 0; mi < 4; mi++)
#pragma unroll
      for (int ni = 0; ni < 4; ni++)
        acc[mi][ni] = __builtin_amdgcn_mfma_f32_16x16x32_bf16(
            af[mi], bf[ni], acc[mi][ni], 0, 0, 0);
  }

  // epilogue: lane holds D[(qd*4+r)][l15] per 16x16 tile
#pragma unroll
  for (int mi = 0; mi < 4; mi++)
#pragma unroll
    for (int ni = 0; ni < 4; ni++) {
      int mBase = m0 + wm + mi * 16 + qd * 4;
      int nn = n0 + wn + ni * 16 + l15;
#pragma unroll
      for (int r = 0; r < 4; r++) {
        int m = mBase + r;
        float v = acc[mi][ni][r];
        if constexpr (EPI == 0) {
          v += bias[nn];
          v = v / (1.0f + __expf(-v));  // silu
          short bvv = f2bf(v);
          int which = n0 / HD;  // block-uniform (768 = 6*128)
          int ncol = nn - which * HD;
          if (which == 0)      o0[(long)m * HD + ncol] = bvv;
          else if (which == 1) o1[(long)m * HD + ncol] = bvv;
          else if (which == 2) o2[(long)m * HD + ncol] = bvv;
          else  // V transposed per batch: Vt[b][d][t]
            o3[((long)(m >> 11) * HD + ncol) * TT + (m & (TT - 1))] = bvv;
        } else if constexpr (EPI == 1) {
          v *= 0.022097086912079608f;  // 1/sqrt(2048)
          v = fmaxf(v, 0.0f);
          v = v * v;
          o0[(long)z * TT * TT + (long)m * TT + nn] = f2bf(v);
        } else if constexpr (EPI == 2) {
          float um = bf2f(umul[(long)z * TT * HD + (long)m * HD + nn]);
          o0[(long)z * TT * HD + (long)m * HD + nn] = f2bf(v * um);
        } else {
          v += bias[nn];
          outf[(long)m * HD + nn] = v;
        }
      }
    }
}

extern "C" void kernel_launch(void* const* d_in, const int* in_sizes, int n_in,
                              void* d_out, int out_size, void* d_ws, size_t ws_size,
                              hipStream_t stream) {
  (void)in_sizes; (void)n_in; (void)out_size; (void)ws_size;
  const float* hid = (const float*)d_in[0];
  const float* lng = (const float*)d_in[1];
  const float* lnb = (const float*)d_in[2];
  const float* Wu  = (const float*)d_in[3];
  const float* bu  = (const float*)d_in[4];
  const float* Wq  = (const float*)d_in[5];
  const float* bq  = (const float*)d_in[6];
  const float* Wk  = (const float*)d_in[7];
  const float* bk  = (const float*)d_in[8];
  const float* Wv  = (const float*)d_in[9];
  const float* bv  = (const float*)d_in[10];
  const float* Wo  = (const float*)d_in[11];
  const float* bo  = (const float*)d_in[12];

  // workspace layout (bytes)
  char* ws = (char*)d_ws;
  short* Wb   = (short*)(ws);                 // 5*589824 bf16 = 5,898,240 B
  float* bcat = (float*)(ws + 5898240);       // 3072 fp32     =    12,288 B
  short* xbf  = (short*)(ws + 5910528);       // 8192x768 bf16 = 12,582,912 B
  short* Ub   = (short*)(ws + 18493440);      // 12,582,912 B
  short* Qb   = (short*)(ws + 31076352);      // 12,582,912 B
  short* Kb   = (short*)(ws + 43659264);      // 12,582,912 B
  short* Vt   = (short*)(ws + 56242176);      // 4 x 768x2048 bf16 = 12,582,912 B
  short* Pb   = (short*)(ws + 68825088);      // 4 x 2048x2048 bf16 = 33,554,432 B
  short* Gb   = (short*)(ws + 102379520);     // 12,582,912 B  (total ~115 MB)

  convert_kernel<<<11520, 256, 0, stream>>>(Wu, Wq, Wk, Wv, Wo, bu, bq, bk, bv, Wb, bcat);
  ln_kernel<<<8192, 256, 0, stream>>>(hid, lng, lnb, xbf);

  // U,Q,K,V = silu(x @ Wcat^T + bcat): M=8192, N=3072, K=768
  gemm_bt<0><<<dim3(24, 64, 1), 256, 0, stream>>>(
      xbf, Wb, 768, 768, 768, 0, 0, Ub, Qb, Kb, Vt, nullptr, bcat, nullptr);

  // P = relu(QK^T/sqrt(T))^2 per batch: M=N=2048, K=768
  gemm_bt<1><<<dim3(16, 16, 4), 256, 0, stream>>>(
      Qb, Kb, 768, 768, 768, (long)TT * HD, (long)TT * HD,
      Pb, nullptr, nullptr, nullptr, nullptr, nullptr, nullptr);

  // G = (P @ V) * U per batch: M=2048, N=768, K=2048  (B operand = Vt, contiguous K)
  gemm_bt<2><<<dim3(6, 16, 4), 256, 0, stream>>>(
      Pb, Vt, 2048, 2048, 2048, (long)TT * TT, (long)HD * TT,
      Gb, nullptr, nullptr, nullptr, nullptr, nullptr, Ub);

  // out = G @ Wo^T + bo: M=8192, N=768, K=768, fp32 out
  gemm_bt<3><<<dim3(6, 64, 1), 256, 0, stream>>>(
      Gb, Wb + 4 * WElem, 768, 768, 768, 0, 0,
      nullptr, nullptr, nullptr, nullptr, (float*)d_out, bo, nullptr);
}